// Round 10
// baseline (194.500 us; speedup 1.0000x reference)
//
#include <hip/hip_runtime.h>
#include <hip/hip_bf16.h>
#include <math.h>

#define B_SZ 2
#define T_LEN 1024
#define DMODEL 1024
#define DINNER 2048
#define DSTATE 16
#define DCONV 4
#define DTRANK 64
#define MTOK (B_SZ * T_LEN)   // 2048 tokens

// chunked scan: channel-per-thread, 16 states in registers
#define NC 32
#define CLEN (T_LEN / NC)                 // 32
#define NCH (B_SZ * DINNER)               // 4096 channels
#define NSTATES (NCH * DSTATE)            // 65536

typedef __bf16 bf16x4 __attribute__((ext_vector_type(4)));
typedef __bf16 bf16x8 __attribute__((ext_vector_type(8)));
typedef float  f32x4  __attribute__((ext_vector_type(4)));

__device__ __forceinline__ float sigmoid_f(float v) { return 1.f / (1.f + __expf(-v)); }

// ---------------------------------------------------------------------------
// one-shot bf16 conversion of x, in_proj_w, out_proj_w + zero-init of xdbl.
// segments in 8-elem groups: x=262144, w_in=524288, w_out=262144, xdbl-zero=24576
// ---------------------------------------------------------------------------
__global__ __launch_bounds__(256) void convert3(const float* __restrict__ x,
                                                const float* __restrict__ w_in,
                                                const float* __restrict__ w_out,
                                                __bf16* __restrict__ xb,
                                                __bf16* __restrict__ wb_in,
                                                __bf16* __restrict__ wb_out,
                                                float* __restrict__ xdbl)
{
    const int gi = blockIdx.x * blockDim.x + threadIdx.x;
    if (gi >= 1048576) {
        const int o = gi - 1048576;            // < 24576
        float4 z = make_float4(0.f, 0.f, 0.f, 0.f);
        reinterpret_cast<float4*>(xdbl)[2 * o]     = z;
        reinterpret_cast<float4*>(xdbl)[2 * o + 1] = z;
        return;
    }
    const float* src; __bf16* dst; int o;
    if (gi < 262144)      { src = x;     dst = xb;     o = gi; }
    else if (gi < 786432) { src = w_in;  dst = wb_in;  o = gi - 262144; }
    else                  { src = w_out; dst = wb_out; o = gi - 786432; }
    float4 a = reinterpret_cast<const float4*>(src)[2 * o];
    float4 b = reinterpret_cast<const float4*>(src)[2 * o + 1];
    bf16x8 v = {(__bf16)a.x, (__bf16)a.y, (__bf16)a.z, (__bf16)a.w,
                (__bf16)b.x, (__bf16)b.y, (__bf16)b.z, (__bf16)b.w};
    reinterpret_cast<bf16x8*>(dst)[o] = v;
}

// ---------------------------------------------------------------------------
// bf16 MFMA GEMM (m97 structure): C[M,N] = A[M,K] * B[N,K]^T, bf16 in, CT out.
// ---------------------------------------------------------------------------
template<int BN, typename CT>
__global__ __launch_bounds__(256) void mfma_gemm_bf16(const __bf16* __restrict__ A, int lda,
                                                      const __bf16* __restrict__ Bm, int ldb,
                                                      CT* __restrict__ C, int ldc, int K)
{
    constexpr int NF = BN / 32;
    constexpr int BCALLS = BN / 32;
    __shared__ __align__(16) __bf16 As[128 * 64];
    __shared__ __align__(16) __bf16 Bs[BN * 64];
    const int tid  = threadIdx.x;
    const int lane = tid & 63;
    const int w    = tid >> 6;
    const int wr   = w >> 1, wc = w & 1;
    const int m0   = blockIdx.y * 128, n0 = blockIdx.x * BN;

    f32x4 acc[4][NF];
    #pragma unroll
    for (int i = 0; i < 4; ++i)
        #pragma unroll
        for (int j = 0; j < NF; ++j) {
            f32x4 z = {0.f, 0.f, 0.f, 0.f};
            acc[i][j] = z;
        }

    const int fr = lane & 15;
    const int kq = (lane >> 4) * 8;

    for (int k0 = 0; k0 < K; k0 += 64) {
        #pragma unroll
        for (int c = 0; c < 4; ++c) {
            const int idx = c * 256 + tid;
            const int row = idx >> 3;
            const int kc  = (idx & 7) * 8;
            __builtin_amdgcn_global_load_lds(
                (const __attribute__((address_space(1))) unsigned int*)(A + (size_t)(m0 + row) * lda + k0 + kc),
                (__attribute__((address_space(3))) unsigned int*)(As + idx * 8),
                16, 0, 0);
        }
        #pragma unroll
        for (int c = 0; c < BCALLS; ++c) {
            const int idx = c * 256 + tid;
            const int row = idx >> 3;
            const int kc  = (idx & 7) * 8;
            __builtin_amdgcn_global_load_lds(
                (const __attribute__((address_space(1))) unsigned int*)(Bm + (size_t)(n0 + row) * ldb + k0 + kc),
                (__attribute__((address_space(3))) unsigned int*)(Bs + idx * 8),
                16, 0, 0);
        }
        __syncthreads();

        bf16x8 af[4][2], bfr[NF][2];
        #pragma unroll
        for (int i = 0; i < 4; ++i) {
            const __bf16* pa = As + (wr * 64 + i * 16 + fr) * 64 + kq;
            af[i][0] = *reinterpret_cast<const bf16x8*>(pa);
            af[i][1] = *reinterpret_cast<const bf16x8*>(pa + 32);
        }
        #pragma unroll
        for (int j = 0; j < NF; ++j) {
            const __bf16* pb = Bs + (wc * (BN / 2) + j * 16 + fr) * 64 + kq;
            bfr[j][0] = *reinterpret_cast<const bf16x8*>(pb);
            bfr[j][1] = *reinterpret_cast<const bf16x8*>(pb + 32);
        }
        #pragma unroll
        for (int i = 0; i < 4; ++i)
            #pragma unroll
            for (int j = 0; j < NF; ++j) {
                acc[i][j] = __builtin_amdgcn_mfma_f32_16x16x32_bf16(af[i][0], bfr[j][0], acc[i][j], 0, 0, 0);
                acc[i][j] = __builtin_amdgcn_mfma_f32_16x16x32_bf16(af[i][1], bfr[j][1], acc[i][j], 0, 0, 0);
            }
        __syncthreads();
    }

    const int crow = (lane >> 4) * 4;
    const int ccol = lane & 15;
    #pragma unroll
    for (int i = 0; i < 4; ++i)
        #pragma unroll
        for (int j = 0; j < NF; ++j) {
            CT* cp = C + (size_t)(m0 + wr * 64 + i * 16 + crow) * ldc
                       + n0 + wc * (BN / 2) + j * 16 + ccol;
            cp[0 * (size_t)ldc] = (CT)acc[i][j][0];
            cp[1 * (size_t)ldc] = (CT)acc[i][j][1];
            cp[2 * (size_t)ldc] = (CT)acc[i][j][2];
            cp[3 * (size_t)ldc] = (CT)acc[i][j][3];
        }
}

// ---------------------------------------------------------------------------
// x_proj split-K with conv-on-the-fly A and atomic accumulation into xdbl.
// A[m][k] = silu(conv(xzb[m-3..m][k])), B = x_proj_w[n][k]. K-chunk per blockIdx.z.
// ---------------------------------------------------------------------------
#define XP_KS 16
#define XP_KC (DINNER / XP_KS)   // 128

__global__ __launch_bounds__(256) void gemm_xproj_splitk(const __bf16* __restrict__ xzb,
                                                         const float* __restrict__ cw,
                                                         const float* __restrict__ cb,
                                                         const float* __restrict__ W,
                                                         float* __restrict__ xdbl)
{
    __shared__ float As[16][68];
    __shared__ float Bs[16][68];
    const int tx = threadIdx.x & 15;
    const int ty = threadIdx.x >> 4;
    const int n0 = blockIdx.x * 64;
    const int m0 = blockIdx.y * 64;
    const int kz = blockIdx.z;
    const int lr = threadIdx.x >> 2;
    const int lc = (threadIdx.x & 3) * 4;

    const int m  = m0 + lr;
    const int tb = m & (T_LEN - 1);

    float acc[4][4] = {};

    for (int k0 = kz * XP_KC; k0 < (kz + 1) * XP_KC; k0 += 16) {
        {
            const int ch0 = k0 + lc;
            float xv[4][4];
            #pragma unroll
            for (int j = 0; j < 4; ++j) {
                if (tb - 3 + j >= 0) {
                    bf16x4 v = *reinterpret_cast<const bf16x4*>(
                        &xzb[(size_t)(m - 3 + j) * (2 * DINNER) + ch0]);
                    xv[j][0] = (float)v[0]; xv[j][1] = (float)v[1];
                    xv[j][2] = (float)v[2]; xv[j][3] = (float)v[3];
                } else {
                    xv[j][0] = xv[j][1] = xv[j][2] = xv[j][3] = 0.f;
                }
            }
            float4 cbv = *reinterpret_cast<const float4*>(&cb[ch0]);
            float cbw[4] = {cbv.x, cbv.y, cbv.z, cbv.w};
            #pragma unroll
            for (int c = 0; c < 4; ++c) {
                float4 wv = *reinterpret_cast<const float4*>(&cw[(ch0 + c) * DCONV]);
                float a = cbw[c];
                a = fmaf(xv[0][c], wv.x, a);
                a = fmaf(xv[1][c], wv.y, a);
                a = fmaf(xv[2][c], wv.z, a);
                a = fmaf(xv[3][c], wv.w, a);
                As[lc + c][lr] = a * sigmoid_f(a);
            }
        }
        {
            int n = n0 + lr;
            float4 v = make_float4(0.f, 0.f, 0.f, 0.f);
            if (n < DTRANK + 2 * DSTATE)
                v = *reinterpret_cast<const float4*>(&W[(size_t)n * DINNER + k0 + lc]);
            Bs[lc + 0][lr] = v.x; Bs[lc + 1][lr] = v.y;
            Bs[lc + 2][lr] = v.z; Bs[lc + 3][lr] = v.w;
        }
        __syncthreads();
        #pragma unroll
        for (int kk = 0; kk < 16; ++kk) {
            float av[4], bv[4];
            #pragma unroll
            for (int i = 0; i < 4; ++i) av[i] = As[kk][ty + 16 * i];
            #pragma unroll
            for (int j = 0; j < 4; ++j) bv[j] = Bs[kk][tx + 16 * j];
            #pragma unroll
            for (int i = 0; i < 4; ++i)
                #pragma unroll
                for (int j = 0; j < 4; ++j)
                    acc[i][j] = fmaf(av[i], bv[j], acc[i][j]);
        }
        __syncthreads();
    }

    #pragma unroll
    for (int i = 0; i < 4; ++i) {
        int mm = m0 + ty + 16 * i;
        #pragma unroll
        for (int j = 0; j < 4; ++j) {
            int n = n0 + tx + 16 * j;
            if (n < 96) unsafeAtomicAdd(&xdbl[(size_t)mm * 96 + n], acc[i][j]);
        }
    }
}

// ---------------------------------------------------------------------------
// dt_proj: dt[m][n] = bf16(softplus(xdbl[m][0:64] . W[n][0:64] + bias[n]))
// ---------------------------------------------------------------------------
__global__ __launch_bounds__(256) void gemm_dtproj(const float* __restrict__ A,      // xdbl, lda 96
                                                   const float* __restrict__ Bm,     // dt_proj_w
                                                   __bf16* __restrict__ C,
                                                   const float* __restrict__ bias)
{
    __shared__ float As[16][68];
    __shared__ float Bs[16][68];
    const int tx = threadIdx.x & 15;
    const int ty = threadIdx.x >> 4;
    const int m0 = blockIdx.y * 64;
    const int n0 = blockIdx.x * 64;
    const int lr = threadIdx.x >> 2;
    const int lc = (threadIdx.x & 3) * 4;

    float acc[4][4] = {};

    for (int k0 = 0; k0 < DTRANK; k0 += 16) {
        {
            float4 v = *reinterpret_cast<const float4*>(&A[(size_t)(m0 + lr) * 96 + k0 + lc]);
            As[lc + 0][lr] = v.x; As[lc + 1][lr] = v.y;
            As[lc + 2][lr] = v.z; As[lc + 3][lr] = v.w;
        }
        {
            float4 v = *reinterpret_cast<const float4*>(&Bm[(size_t)(n0 + lr) * DTRANK + k0 + lc]);
            Bs[lc + 0][lr] = v.x; Bs[lc + 1][lr] = v.y;
            Bs[lc + 2][lr] = v.z; Bs[lc + 3][lr] = v.w;
        }
        __syncthreads();
        #pragma unroll
        for (int kk = 0; kk < 16; ++kk) {
            float av[4], bv[4];
            #pragma unroll
            for (int i = 0; i < 4; ++i) av[i] = As[kk][ty + 16 * i];
            #pragma unroll
            for (int j = 0; j < 4; ++j) bv[j] = Bs[kk][tx + 16 * j];
            #pragma unroll
            for (int i = 0; i < 4; ++i)
                #pragma unroll
                for (int j = 0; j < 4; ++j)
                    acc[i][j] = fmaf(av[i], bv[j], acc[i][j]);
        }
        __syncthreads();
    }

    #pragma unroll
    for (int i = 0; i < 4; ++i) {
        int m = m0 + ty + 16 * i;
        #pragma unroll
        for (int j = 0; j < 4; ++j) {
            int n = n0 + tx + 16 * j;
            float v = acc[i][j] + bias[n];
            v = (v > 20.f) ? v : log1pf(__expf(v));
            C[(size_t)m * DINNER + n] = (__bf16)v;
        }
    }
}

// ---------------------------------------------------------------------------
// chunked selective scan, channel-per-thread, conv-on-the-fly, 16 states in regs.
// ---------------------------------------------------------------------------
__global__ __launch_bounds__(256) void scan_pass1(const __bf16* __restrict__ dtb,
                                                  const __bf16* __restrict__ xzb,
                                                  const float* __restrict__ cw,
                                                  const float* __restrict__ cb,
                                                  const float* __restrict__ xdbl,
                                                  const float* __restrict__ A_log,
                                                  float* __restrict__ Pb,
                                                  float* __restrict__ Bb)
{
    __shared__ float sB[CLEN][16];
    const int tid = threadIdx.x;
    const int g   = blockIdx.x * 256 + tid;     // global channel 0..4095
    const int c   = blockIdx.y;
    const int b   = g >> 11;
    const int d   = g & (DINNER - 1);
    const int m0  = b * T_LEN + c * CLEN;

    if (tid < CLEN * 4) {
        int t = tid >> 2, s4 = (tid & 3) * 4;
        *reinterpret_cast<float4*>(&sB[t][s4]) =
            *reinterpret_cast<const float4*>(&xdbl[(size_t)(m0 + t) * 96 + DTRANK + s4]);
    }
    __syncthreads();

    float a[DSTATE], h[DSTATE];
    #pragma unroll
    for (int s4 = 0; s4 < DSTATE; s4 += 4) {
        float4 v = *reinterpret_cast<const float4*>(&A_log[d * DSTATE + s4]);
        a[s4 + 0] = -__expf(v.x); a[s4 + 1] = -__expf(v.y);
        a[s4 + 2] = -__expf(v.z); a[s4 + 3] = -__expf(v.w);
        h[s4 + 0] = 0.f; h[s4 + 1] = 0.f; h[s4 + 2] = 0.f; h[s4 + 3] = 0.f;
    }

    const float4 wv = *reinterpret_cast<const float4*>(&cw[d * DCONV]);
    const float cbv = cb[d];
    float xw0, xw1, xw2;
    if (c > 0) {
        xw0 = (float)xzb[(size_t)(m0 - 3) * (2 * DINNER) + d];
        xw1 = (float)xzb[(size_t)(m0 - 2) * (2 * DINNER) + d];
        xw2 = (float)xzb[(size_t)(m0 - 1) * (2 * DINNER) + d];
    } else { xw0 = xw1 = xw2 = 0.f; }

    float sumdt = 0.f;
    float dtc = (float)dtb[(size_t)m0 * DINNER + d];
    float xzc = (float)xzb[(size_t)m0 * (2 * DINNER) + d];
    for (int t = 0; t < CLEN; ++t) {
        float dtn = 0.f, xzn = 0.f;
        if (t + 1 < CLEN) {
            dtn = (float)dtb[(size_t)(m0 + t + 1) * DINNER + d];
            xzn = (float)xzb[(size_t)(m0 + t + 1) * (2 * DINNER) + d];
        }
        float xc = cbv;
        xc = fmaf(xw0, wv.x, xc); xc = fmaf(xw1, wv.y, xc);
        xc = fmaf(xw2, wv.z, xc); xc = fmaf(xzc, wv.w, xc);
        xc = xc * sigmoid_f(xc);
        sumdt += dtc;
        const float u = dtc * xc;
        #pragma unroll
        for (int s = 0; s < DSTATE; ++s) {
            const float dA = __expf(dtc * a[s]);
            h[s] = fmaf(dA, h[s], u * sB[t][s]);
        }
        xw0 = xw1; xw1 = xw2; xw2 = xzc;
        dtc = dtn; xzc = xzn;
    }

    float* pp = Pb + ((size_t)c * NCH + g) * DSTATE;
    float* bp = Bb + ((size_t)c * NCH + g) * DSTATE;
    #pragma unroll
    for (int s4 = 0; s4 < DSTATE; s4 += 4) {
        float4 pv = {__expf(a[s4] * sumdt), __expf(a[s4 + 1] * sumdt),
                     __expf(a[s4 + 2] * sumdt), __expf(a[s4 + 3] * sumdt)};
        *reinterpret_cast<float4*>(pp + s4) = pv;
        float4 hv = {h[s4], h[s4 + 1], h[s4 + 2], h[s4 + 3]};
        *reinterpret_cast<float4*>(bp + s4) = hv;
    }
}

__global__ __launch_bounds__(256) void scan_pass2(const float* __restrict__ Pb,
                                                  float* __restrict__ Bb)
{
    const int idx = blockIdx.x * blockDim.x + threadIdx.x;  // 0..NSTATES-1
    float h = 0.f;
    #pragma unroll
    for (int c = 0; c < NC; ++c) {
        const size_t o = (size_t)c * NSTATES + idx;
        const float P  = Pb[o];
        const float Bv = Bb[o];
        Bb[o] = h;
        h = fmaf(P, h, Bv);
    }
}

__global__ __launch_bounds__(256) void scan_pass3(const __bf16* __restrict__ dtb,
                                                  const __bf16* __restrict__ xzb,
                                                  const float* __restrict__ cw,
                                                  const float* __restrict__ cb,
                                                  const float* __restrict__ xdbl,
                                                  const float* __restrict__ Hs,
                                                  const float* __restrict__ A_log,
                                                  const float* __restrict__ Dp,
                                                  __bf16* __restrict__ yMb)
{
    __shared__ float sBC[CLEN][32];   // cols 0..15 = B, 16..31 = C
    const int tid = threadIdx.x;
    const int g   = blockIdx.x * 256 + tid;
    const int c   = blockIdx.y;
    const int b   = g >> 11;
    const int d   = g & (DINNER - 1);
    const int m0  = b * T_LEN + c * CLEN;

    {
        int t = tid >> 3, col = (tid & 7) * 4;
        if (t < CLEN)
            *reinterpret_cast<float4*>(&sBC[t][col]) =
                *reinterpret_cast<const float4*>(&xdbl[(size_t)(m0 + t) * 96 + DTRANK + col]);
    }
    __syncthreads();

    float a[DSTATE], h[DSTATE];
    #pragma unroll
    for (int s4 = 0; s4 < DSTATE; s4 += 4) {
        float4 v = *reinterpret_cast<const float4*>(&A_log[d * DSTATE + s4]);
        a[s4 + 0] = -__expf(v.x); a[s4 + 1] = -__expf(v.y);
        a[s4 + 2] = -__expf(v.z); a[s4 + 3] = -__expf(v.w);
        float4 hv = *reinterpret_cast<const float4*>(
            Hs + ((size_t)c * NCH + g) * DSTATE + s4);
        h[s4 + 0] = hv.x; h[s4 + 1] = hv.y; h[s4 + 2] = hv.z; h[s4 + 3] = hv.w;
    }
    const float Dv = Dp[d];

    const float4 wv = *reinterpret_cast<const float4*>(&cw[d * DCONV]);
    const float cbv = cb[d];
    float xw0, xw1, xw2;
    if (c > 0) {
        xw0 = (float)xzb[(size_t)(m0 - 3) * (2 * DINNER) + d];
        xw1 = (float)xzb[(size_t)(m0 - 2) * (2 * DINNER) + d];
        xw2 = (float)xzb[(size_t)(m0 - 1) * (2 * DINNER) + d];
    } else { xw0 = xw1 = xw2 = 0.f; }

    float dtc = (float)dtb[(size_t)m0 * DINNER + d];
    float xzc = (float)xzb[(size_t)m0 * (2 * DINNER) + d];
    float zc  = (float)xzb[(size_t)m0 * (2 * DINNER) + DINNER + d];
    for (int t = 0; t < CLEN; ++t) {
        float dtn = 0.f, xzn = 0.f, zn = 0.f;
        if (t + 1 < CLEN) {
            dtn = (float)dtb[(size_t)(m0 + t + 1) * DINNER + d];
            xzn = (float)xzb[(size_t)(m0 + t + 1) * (2 * DINNER) + d];
            zn  = (float)xzb[(size_t)(m0 + t + 1) * (2 * DINNER) + DINNER + d];
        }
        float xc = cbv;
        xc = fmaf(xw0, wv.x, xc); xc = fmaf(xw1, wv.y, xc);
        xc = fmaf(xw2, wv.z, xc); xc = fmaf(xzc, wv.w, xc);
        xc = xc * sigmoid_f(xc);
        const float u = dtc * xc;
        float y0 = 0.f, y1 = 0.f, y2 = 0.f, y3 = 0.f;
        #pragma unroll
        for (int s = 0; s < DSTATE; s += 4) {
            float dA0 = __expf(dtc * a[s + 0]);
            float dA1 = __expf(dtc * a[s + 1]);
            float dA2 = __expf(dtc * a[s + 2]);
            float dA3 = __expf(dtc * a[s + 3]);
            h[s + 0] = fmaf(dA0, h[s + 0], u * sBC[t][s + 0]);
            h[s + 1] = fmaf(dA1, h[s + 1], u * sBC[t][s + 1]);
            h[s + 2] = fmaf(dA2, h[s + 2], u * sBC[t][s + 2]);
            h[s + 3] = fmaf(dA3, h[s + 3], u * sBC[t][s + 3]);
            y0 = fmaf(h[s + 0], sBC[t][16 + s + 0], y0);
            y1 = fmaf(h[s + 1], sBC[t][16 + s + 1], y1);
            y2 = fmaf(h[s + 2], sBC[t][16 + s + 2], y2);
            y3 = fmaf(h[s + 3], sBC[t][16 + s + 3], y3);
        }
        float y = (y0 + y1) + (y2 + y3) + xc * Dv;
        const float gate = zc * sigmoid_f(zc);
        yMb[(size_t)(m0 + t) * DINNER + d] = (__bf16)(y * gate);
        xw0 = xw1; xw1 = xw2; xw2 = xzc;
        dtc = dtn; xzc = xzn; zc = zn;
    }
}

extern "C" void kernel_launch(void* const* d_in, const int* in_sizes, int n_in,
                              void* d_out, int out_size, void* d_ws, size_t ws_size,
                              hipStream_t stream) {
    const float* x         = (const float*)d_in[0];
    const float* in_proj_w = (const float*)d_in[1];
    const float* conv_w    = (const float*)d_in[2];
    const float* conv_b    = (const float*)d_in[3];
    const float* x_proj_w  = (const float*)d_in[4];
    const float* dt_proj_w = (const float*)d_in[5];
    const float* dt_proj_b = (const float*)d_in[6];
    const float* A_log     = (const float*)d_in[7];
    const float* D_param   = (const float*)d_in[8];
    const float* out_proj_w= (const float*)d_in[9];
    float* out = (float*)d_out;

    // ws layout (float units), no aliasing:
    // [0,4M)   xzb bf16 [2048][4096]
    // [4M,5M)  xb bf16      [5M,7M) wb_in bf16    [7M,8M) wb_out bf16
    // [8M,10M) dtb bf16
    // [10M,10.25M) xdbl fp32 (zero-init in convert3, atomic-accumulated)
    // [11M,13M) Pb fp32     [13M,15M) Bb fp32
    // [15M,17M) yMb bf16
    float* ws = (float*)d_ws;
    const size_t M1 = (size_t)1024 * 1024;
    __bf16* xzb    = (__bf16*)ws;
    __bf16* xb     = (__bf16*)(ws + 4 * M1);
    __bf16* wb_in  = (__bf16*)(ws + 5 * M1);
    __bf16* wb_out = (__bf16*)(ws + 7 * M1);
    __bf16* dtb    = (__bf16*)(ws + 8 * M1);
    float*  xdbl   = ws + 10 * M1;
    float*  Pb     = ws + 11 * M1;
    float*  Bb     = ws + 13 * M1;
    __bf16* yMb    = (__bf16*)(ws + 15 * M1);

    dim3 blk(256);

    // 0. bf16 conversions + xdbl zero-init (one dispatch)
    convert3<<<dim3(4192), blk, 0, stream>>>(x, in_proj_w, out_proj_w, xb, wb_in, wb_out, xdbl);

    // 1. in_proj (bf16 MFMA): xzb[m][4096] (bf16 out)
    mfma_gemm_bf16<128, __bf16><<<dim3((2 * DINNER) / 128, MTOK / 128), blk, 0, stream>>>(
        xb, DMODEL, wb_in, DMODEL, xzb, 2 * DINNER, DMODEL);

    // 2. x_proj split-K with fused conv, atomic accumulate -> xdbl[m][96]
    gemm_xproj_splitk<<<dim3(2, MTOK / 64, XP_KS), blk, 0, stream>>>(
        xzb, conv_w, conv_b, x_proj_w, xdbl);

    // 3. dt_proj: dtb[m][i] = bf16(softplus(...))
    gemm_dtproj<<<dim3(DINNER / 64, MTOK / 64), blk, 0, stream>>>(xdbl, dt_proj_w, dtb, dt_proj_b);

    // 4. chunked scan with fused conv + gate epilogue -> yMb bf16 [m][d]
    scan_pass1<<<dim3(NCH / 256, NC), blk, 0, stream>>>(dtb, xzb, conv_w, conv_b, xdbl, A_log, Pb, Bb);
    scan_pass2<<<dim3(NSTATES / 256), blk, 0, stream>>>(Pb, Bb);
    scan_pass3<<<dim3(NCH / 256, NC), blk, 0, stream>>>(dtb, xzb, conv_w, conv_b, xdbl, Bb, A_log, D_param, yMb);

    // 5. out_proj (bf16 MFMA): out[m][1024] (fp32 out)
    mfma_gemm_bf16<64, float><<<dim3(DMODEL / 64, MTOK / 128), blk, 0, stream>>>(
        yMb, DINNER, wb_out, DINNER, out, DMODEL, DINNER);
}

// Round 11
// 177.779 us; speedup vs baseline: 1.0941x; 1.0941x over previous
//
#include <hip/hip_runtime.h>
#include <hip/hip_bf16.h>
#include <math.h>

#define B_SZ 2
#define T_LEN 1024
#define DMODEL 1024
#define DINNER 2048
#define DSTATE 16
#define DCONV 4
#define DTRANK 64
#define MTOK (B_SZ * T_LEN)   // 2048 tokens

// chunked scan: channel-per-thread, 16 states in registers
#define NC 32
#define CLEN (T_LEN / NC)                 // 32
#define NCH (B_SZ * DINNER)               // 4096 channels
#define NSTATES (NCH * DSTATE)            // 65536

// x_proj MFMA split-K ways
#define XPK 8
#define XPKC (DINNER / XPK)               // 256

typedef __bf16 bf16x4 __attribute__((ext_vector_type(4)));
typedef __bf16 bf16x8 __attribute__((ext_vector_type(8)));
typedef float  f32x4  __attribute__((ext_vector_type(4)));

__device__ __forceinline__ float sigmoid_f(float v) { return 1.f / (1.f + __expf(-v)); }

// ---------------------------------------------------------------------------
// one-shot bf16 conversion of x, in_proj_w, out_proj_w, x_proj_w + zero xdbl.
// 8-elem groups: x=262144, w_in=524288, w_out=262144, w_xp=24576, zero=24576
// ---------------------------------------------------------------------------
__global__ __launch_bounds__(256) void convert4(const float* __restrict__ x,
                                                const float* __restrict__ w_in,
                                                const float* __restrict__ w_out,
                                                const float* __restrict__ w_xp,
                                                __bf16* __restrict__ xb,
                                                __bf16* __restrict__ wb_in,
                                                __bf16* __restrict__ wb_out,
                                                __bf16* __restrict__ wxp,
                                                float* __restrict__ xdbl)
{
    const int gi = blockIdx.x * blockDim.x + threadIdx.x;
    if (gi >= 1073152) {
        const int o = gi - 1073152;            // < 24576
        float4 z = make_float4(0.f, 0.f, 0.f, 0.f);
        reinterpret_cast<float4*>(xdbl)[2 * o]     = z;
        reinterpret_cast<float4*>(xdbl)[2 * o + 1] = z;
        return;
    }
    const float* src; __bf16* dst; int o;
    if (gi < 262144)       { src = x;     dst = xb;     o = gi; }
    else if (gi < 786432)  { src = w_in;  dst = wb_in;  o = gi - 262144; }
    else if (gi < 1048576) { src = w_out; dst = wb_out; o = gi - 786432; }
    else                   { src = w_xp;  dst = wxp;    o = gi - 1048576; }
    float4 a = reinterpret_cast<const float4*>(src)[2 * o];
    float4 b = reinterpret_cast<const float4*>(src)[2 * o + 1];
    bf16x8 v = {(__bf16)a.x, (__bf16)a.y, (__bf16)a.z, (__bf16)a.w,
                (__bf16)b.x, (__bf16)b.y, (__bf16)b.z, (__bf16)b.w};
    reinterpret_cast<bf16x8*>(dst)[o] = v;
}

// ---------------------------------------------------------------------------
// bf16 MFMA GEMM (m97 structure): C[M,N] = A[M,K] * B[N,K]^T, bf16 in, CT out.
// ---------------------------------------------------------------------------
template<int BN, typename CT>
__global__ __launch_bounds__(256) void mfma_gemm_bf16(const __bf16* __restrict__ A, int lda,
                                                      const __bf16* __restrict__ Bm, int ldb,
                                                      CT* __restrict__ C, int ldc, int K)
{
    constexpr int NF = BN / 32;
    constexpr int BCALLS = BN / 32;
    __shared__ __align__(16) __bf16 As[128 * 64];
    __shared__ __align__(16) __bf16 Bs[BN * 64];
    const int tid  = threadIdx.x;
    const int lane = tid & 63;
    const int w    = tid >> 6;
    const int wr   = w >> 1, wc = w & 1;
    const int m0   = blockIdx.y * 128, n0 = blockIdx.x * BN;

    f32x4 acc[4][NF];
    #pragma unroll
    for (int i = 0; i < 4; ++i)
        #pragma unroll
        for (int j = 0; j < NF; ++j) {
            f32x4 z = {0.f, 0.f, 0.f, 0.f};
            acc[i][j] = z;
        }

    const int fr = lane & 15;
    const int kq = (lane >> 4) * 8;

    for (int k0 = 0; k0 < K; k0 += 64) {
        #pragma unroll
        for (int c = 0; c < 4; ++c) {
            const int idx = c * 256 + tid;
            const int row = idx >> 3;
            const int kc  = (idx & 7) * 8;
            __builtin_amdgcn_global_load_lds(
                (const __attribute__((address_space(1))) unsigned int*)(A + (size_t)(m0 + row) * lda + k0 + kc),
                (__attribute__((address_space(3))) unsigned int*)(As + idx * 8),
                16, 0, 0);
        }
        #pragma unroll
        for (int c = 0; c < BCALLS; ++c) {
            const int idx = c * 256 + tid;
            const int row = idx >> 3;
            const int kc  = (idx & 7) * 8;
            __builtin_amdgcn_global_load_lds(
                (const __attribute__((address_space(1))) unsigned int*)(Bm + (size_t)(n0 + row) * ldb + k0 + kc),
                (__attribute__((address_space(3))) unsigned int*)(Bs + idx * 8),
                16, 0, 0);
        }
        __syncthreads();

        bf16x8 af[4][2], bfr[NF][2];
        #pragma unroll
        for (int i = 0; i < 4; ++i) {
            const __bf16* pa = As + (wr * 64 + i * 16 + fr) * 64 + kq;
            af[i][0] = *reinterpret_cast<const bf16x8*>(pa);
            af[i][1] = *reinterpret_cast<const bf16x8*>(pa + 32);
        }
        #pragma unroll
        for (int j = 0; j < NF; ++j) {
            const __bf16* pb = Bs + (wc * (BN / 2) + j * 16 + fr) * 64 + kq;
            bfr[j][0] = *reinterpret_cast<const bf16x8*>(pb);
            bfr[j][1] = *reinterpret_cast<const bf16x8*>(pb + 32);
        }
        #pragma unroll
        for (int i = 0; i < 4; ++i)
            #pragma unroll
            for (int j = 0; j < NF; ++j) {
                acc[i][j] = __builtin_amdgcn_mfma_f32_16x16x32_bf16(af[i][0], bfr[j][0], acc[i][j], 0, 0, 0);
                acc[i][j] = __builtin_amdgcn_mfma_f32_16x16x32_bf16(af[i][1], bfr[j][1], acc[i][j], 0, 0, 0);
            }
        __syncthreads();
    }

    const int crow = (lane >> 4) * 4;
    const int ccol = lane & 15;
    #pragma unroll
    for (int i = 0; i < 4; ++i)
        #pragma unroll
        for (int j = 0; j < NF; ++j) {
            CT* cp = C + (size_t)(m0 + wr * 64 + i * 16 + crow) * ldc
                       + n0 + wc * (BN / 2) + j * 16 + ccol;
            cp[0 * (size_t)ldc] = (CT)acc[i][j][0];
            cp[1 * (size_t)ldc] = (CT)acc[i][j][1];
            cp[2 * (size_t)ldc] = (CT)acc[i][j][2];
            cp[3 * (size_t)ldc] = (CT)acc[i][j][3];
        }
}

// ---------------------------------------------------------------------------
// x_proj MFMA split-K: xdbl[m][n] += xsb[m][k] * wxp[n][k] over K-chunk kz.
// 128x32 tile, grid (3, 16, XPK), atomic fp32 accumulate.
// ---------------------------------------------------------------------------
__global__ __launch_bounds__(256) void mfma_xproj(const __bf16* __restrict__ A,    // xsb [2048][2048]
                                                  const __bf16* __restrict__ Bm,   // wxp [96][2048]
                                                  float* __restrict__ xdbl)
{
    __shared__ __align__(16) __bf16 As[128 * 64];
    __shared__ __align__(16) __bf16 Bs[32 * 64];
    const int tid  = threadIdx.x;
    const int lane = tid & 63;
    const int w    = tid >> 6;
    const int wr   = w >> 1, wc = w & 1;
    const int m0   = blockIdx.y * 128, n0 = blockIdx.x * 32;
    const int kbeg = blockIdx.z * XPKC;

    f32x4 acc[4];
    #pragma unroll
    for (int i = 0; i < 4; ++i) { f32x4 z = {0.f, 0.f, 0.f, 0.f}; acc[i] = z; }

    const int fr = lane & 15;
    const int kq = (lane >> 4) * 8;

    for (int k0 = kbeg; k0 < kbeg + XPKC; k0 += 64) {
        #pragma unroll
        for (int c = 0; c < 4; ++c) {
            const int idx = c * 256 + tid;
            const int row = idx >> 3;
            const int kc  = (idx & 7) * 8;
            __builtin_amdgcn_global_load_lds(
                (const __attribute__((address_space(1))) unsigned int*)(A + (size_t)(m0 + row) * DINNER + k0 + kc),
                (__attribute__((address_space(3))) unsigned int*)(As + idx * 8),
                16, 0, 0);
        }
        {
            const int row = tid >> 3;            // 0..31
            const int kc  = (tid & 7) * 8;
            __builtin_amdgcn_global_load_lds(
                (const __attribute__((address_space(1))) unsigned int*)(Bm + (size_t)(n0 + row) * DINNER + k0 + kc),
                (__attribute__((address_space(3))) unsigned int*)(Bs + tid * 8),
                16, 0, 0);
        }
        __syncthreads();

        bf16x8 af[4][2], bfr[2];
        #pragma unroll
        for (int i = 0; i < 4; ++i) {
            const __bf16* pa = As + (wr * 64 + i * 16 + fr) * 64 + kq;
            af[i][0] = *reinterpret_cast<const bf16x8*>(pa);
            af[i][1] = *reinterpret_cast<const bf16x8*>(pa + 32);
        }
        {
            const __bf16* pb = Bs + (wc * 16 + fr) * 64 + kq;
            bfr[0] = *reinterpret_cast<const bf16x8*>(pb);
            bfr[1] = *reinterpret_cast<const bf16x8*>(pb + 32);
        }
        #pragma unroll
        for (int i = 0; i < 4; ++i) {
            acc[i] = __builtin_amdgcn_mfma_f32_16x16x32_bf16(af[i][0], bfr[0], acc[i], 0, 0, 0);
            acc[i] = __builtin_amdgcn_mfma_f32_16x16x32_bf16(af[i][1], bfr[1], acc[i], 0, 0, 0);
        }
        __syncthreads();
    }

    const int crow = (lane >> 4) * 4;
    const int ccol = lane & 15;
    const int n = n0 + wc * 16 + ccol;   // < 96
    #pragma unroll
    for (int i = 0; i < 4; ++i) {
        const int m = m0 + wr * 64 + i * 16 + crow;
        unsafeAtomicAdd(&xdbl[(size_t)(m + 0) * 96 + n], acc[i][0]);
        unsafeAtomicAdd(&xdbl[(size_t)(m + 1) * 96 + n], acc[i][1]);
        unsafeAtomicAdd(&xdbl[(size_t)(m + 2) * 96 + n], acc[i][2]);
        unsafeAtomicAdd(&xdbl[(size_t)(m + 3) * 96 + n], acc[i][3]);
    }
}

// ---------------------------------------------------------------------------
// causal depthwise conv (k=4, left pad 3) + bias + SiLU; bf16 in/out
// ---------------------------------------------------------------------------
__global__ __launch_bounds__(256) void conv_silu_kernel(const __bf16* __restrict__ xzb,
                                                        const float* __restrict__ cw,
                                                        const float* __restrict__ cb,
                                                        __bf16* __restrict__ xsb)
{
    int tid = blockIdx.x * blockDim.x + threadIdx.x;  // b*T*DINNER + t*DINNER + d
    int d = tid & (DINNER - 1);
    int t = (tid >> 11) & (T_LEN - 1);
    int b = tid >> 21;
    float acc = cb[d];
    const float4 w = *reinterpret_cast<const float4*>(&cw[d * DCONV]);
    float wv[4] = {w.x, w.y, w.z, w.w};
    #pragma unroll
    for (int j = 0; j < DCONV; ++j) {
        int tt = t - (DCONV - 1) + j;
        if (tt >= 0)
            acc = fmaf((float)xzb[((size_t)(b * T_LEN + tt)) * (2 * DINNER) + d], wv[j], acc);
    }
    xsb[tid] = (__bf16)(acc * sigmoid_f(acc));
}

// ---------------------------------------------------------------------------
// dt_proj: dt[m][n] = bf16(softplus(xdbl[m][0:64] . W[n][0:64] + bias[n]))
// ---------------------------------------------------------------------------
__global__ __launch_bounds__(256) void gemm_dtproj(const float* __restrict__ A,      // xdbl, lda 96
                                                   const float* __restrict__ Bm,     // dt_proj_w
                                                   __bf16* __restrict__ C,
                                                   const float* __restrict__ bias)
{
    __shared__ float As[16][68];
    __shared__ float Bs[16][68];
    const int tx = threadIdx.x & 15;
    const int ty = threadIdx.x >> 4;
    const int m0 = blockIdx.y * 64;
    const int n0 = blockIdx.x * 64;
    const int lr = threadIdx.x >> 2;
    const int lc = (threadIdx.x & 3) * 4;

    float acc[4][4] = {};

    for (int k0 = 0; k0 < DTRANK; k0 += 16) {
        {
            float4 v = *reinterpret_cast<const float4*>(&A[(size_t)(m0 + lr) * 96 + k0 + lc]);
            As[lc + 0][lr] = v.x; As[lc + 1][lr] = v.y;
            As[lc + 2][lr] = v.z; As[lc + 3][lr] = v.w;
        }
        {
            float4 v = *reinterpret_cast<const float4*>(&Bm[(size_t)(n0 + lr) * DTRANK + k0 + lc]);
            Bs[lc + 0][lr] = v.x; Bs[lc + 1][lr] = v.y;
            Bs[lc + 2][lr] = v.z; Bs[lc + 3][lr] = v.w;
        }
        __syncthreads();
        #pragma unroll
        for (int kk = 0; kk < 16; ++kk) {
            float av[4], bv[4];
            #pragma unroll
            for (int i = 0; i < 4; ++i) av[i] = As[kk][ty + 16 * i];
            #pragma unroll
            for (int j = 0; j < 4; ++j) bv[j] = Bs[kk][tx + 16 * j];
            #pragma unroll
            for (int i = 0; i < 4; ++i)
                #pragma unroll
                for (int j = 0; j < 4; ++j)
                    acc[i][j] = fmaf(av[i], bv[j], acc[i][j]);
        }
        __syncthreads();
    }

    #pragma unroll
    for (int i = 0; i < 4; ++i) {
        int m = m0 + ty + 16 * i;
        #pragma unroll
        for (int j = 0; j < 4; ++j) {
            int n = n0 + tx + 16 * j;
            float v = acc[i][j] + bias[n];
            v = (v > 20.f) ? v : log1pf(__expf(v));
            C[(size_t)m * DINNER + n] = (__bf16)v;
        }
    }
}

// ---------------------------------------------------------------------------
// chunked selective scan, channel-per-thread, 16 states in registers.
// ---------------------------------------------------------------------------
__global__ __launch_bounds__(256) void scan_pass1(const __bf16* __restrict__ dtb,
                                                  const __bf16* __restrict__ xsb,
                                                  const float* __restrict__ xdbl,
                                                  const float* __restrict__ A_log,
                                                  float* __restrict__ Pb,
                                                  float* __restrict__ Bb)
{
    __shared__ float sB[CLEN][16];
    const int tid = threadIdx.x;
    const int g   = blockIdx.x * 256 + tid;     // global channel 0..4095
    const int c   = blockIdx.y;
    const int b   = g >> 11;
    const int d   = g & (DINNER - 1);
    const int m0  = b * T_LEN + c * CLEN;

    if (tid < CLEN * 4) {
        int t = tid >> 2, s4 = (tid & 3) * 4;
        *reinterpret_cast<float4*>(&sB[t][s4]) =
            *reinterpret_cast<const float4*>(&xdbl[(size_t)(m0 + t) * 96 + DTRANK + s4]);
    }
    __syncthreads();

    float a[DSTATE], h[DSTATE];
    #pragma unroll
    for (int s4 = 0; s4 < DSTATE; s4 += 4) {
        float4 v = *reinterpret_cast<const float4*>(&A_log[d * DSTATE + s4]);
        a[s4 + 0] = -__expf(v.x); a[s4 + 1] = -__expf(v.y);
        a[s4 + 2] = -__expf(v.z); a[s4 + 3] = -__expf(v.w);
        h[s4 + 0] = 0.f; h[s4 + 1] = 0.f; h[s4 + 2] = 0.f; h[s4 + 3] = 0.f;
    }

    float sumdt = 0.f;
    float dtc = (float)dtb[(size_t)m0 * DINNER + d];
    float xc  = (float)xsb[(size_t)m0 * DINNER + d];
    for (int t = 0; t < CLEN; ++t) {
        float dtn = 0.f, xn = 0.f;
        if (t + 1 < CLEN) {
            dtn = (float)dtb[(size_t)(m0 + t + 1) * DINNER + d];
            xn  = (float)xsb[(size_t)(m0 + t + 1) * DINNER + d];
        }
        sumdt += dtc;
        const float u = dtc * xc;
        #pragma unroll
        for (int s = 0; s < DSTATE; ++s) {
            const float dA = __expf(dtc * a[s]);
            h[s] = fmaf(dA, h[s], u * sB[t][s]);
        }
        dtc = dtn; xc = xn;
    }

    float* pp = Pb + ((size_t)c * NCH + g) * DSTATE;
    float* bp = Bb + ((size_t)c * NCH + g) * DSTATE;
    #pragma unroll
    for (int s4 = 0; s4 < DSTATE; s4 += 4) {
        float4 pv = {__expf(a[s4] * sumdt), __expf(a[s4 + 1] * sumdt),
                     __expf(a[s4 + 2] * sumdt), __expf(a[s4 + 3] * sumdt)};
        *reinterpret_cast<float4*>(pp + s4) = pv;
        float4 hv = {h[s4], h[s4 + 1], h[s4 + 2], h[s4 + 3]};
        *reinterpret_cast<float4*>(bp + s4) = hv;
    }
}

__global__ __launch_bounds__(256) void scan_pass2(const float* __restrict__ Pb,
                                                  float* __restrict__ Bb)
{
    const int idx = blockIdx.x * blockDim.x + threadIdx.x;  // 0..NSTATES-1
    float h = 0.f;
    #pragma unroll
    for (int c = 0; c < NC; ++c) {
        const size_t o = (size_t)c * NSTATES + idx;
        const float P  = Pb[o];
        const float Bv = Bb[o];
        Bb[o] = h;
        h = fmaf(P, h, Bv);
    }
}

__global__ __launch_bounds__(256) void scan_pass3(const __bf16* __restrict__ dtb,
                                                  const __bf16* __restrict__ xsb,
                                                  const float* __restrict__ xdbl,
                                                  const float* __restrict__ Hs,
                                                  const float* __restrict__ A_log,
                                                  const float* __restrict__ Dp,
                                                  const __bf16* __restrict__ xzb,
                                                  __bf16* __restrict__ yMb)
{
    __shared__ float sBC[CLEN][32];   // cols 0..15 = B, 16..31 = C
    const int tid = threadIdx.x;
    const int g   = blockIdx.x * 256 + tid;
    const int c   = blockIdx.y;
    const int b   = g >> 11;
    const int d   = g & (DINNER - 1);
    const int m0  = b * T_LEN + c * CLEN;

    {
        int t = tid >> 3, col = (tid & 7) * 4;
        if (t < CLEN)
            *reinterpret_cast<float4*>(&sBC[t][col]) =
                *reinterpret_cast<const float4*>(&xdbl[(size_t)(m0 + t) * 96 + DTRANK + col]);
    }
    __syncthreads();

    float a[DSTATE], h[DSTATE];
    #pragma unroll
    for (int s4 = 0; s4 < DSTATE; s4 += 4) {
        float4 v = *reinterpret_cast<const float4*>(&A_log[d * DSTATE + s4]);
        a[s4 + 0] = -__expf(v.x); a[s4 + 1] = -__expf(v.y);
        a[s4 + 2] = -__expf(v.z); a[s4 + 3] = -__expf(v.w);
        float4 hv = *reinterpret_cast<const float4*>(
            Hs + ((size_t)c * NCH + g) * DSTATE + s4);
        h[s4 + 0] = hv.x; h[s4 + 1] = hv.y; h[s4 + 2] = hv.z; h[s4 + 3] = hv.w;
    }
    const float Dv = Dp[d];

    float dtc = (float)dtb[(size_t)m0 * DINNER + d];
    float xc  = (float)xsb[(size_t)m0 * DINNER + d];
    float zc  = (float)xzb[(size_t)m0 * (2 * DINNER) + DINNER + d];
    for (int t = 0; t < CLEN; ++t) {
        float dtn = 0.f, xn = 0.f, zn = 0.f;
        if (t + 1 < CLEN) {
            dtn = (float)dtb[(size_t)(m0 + t + 1) * DINNER + d];
            xn  = (float)xsb[(size_t)(m0 + t + 1) * DINNER + d];
            zn  = (float)xzb[(size_t)(m0 + t + 1) * (2 * DINNER) + DINNER + d];
        }
        const float u = dtc * xc;
        float y0 = 0.f, y1 = 0.f, y2 = 0.f, y3 = 0.f;
        #pragma unroll
        for (int s = 0; s < DSTATE; s += 4) {
            float dA0 = __expf(dtc * a[s + 0]);
            float dA1 = __expf(dtc * a[s + 1]);
            float dA2 = __expf(dtc * a[s + 2]);
            float dA3 = __expf(dtc * a[s + 3]);
            h[s + 0] = fmaf(dA0, h[s + 0], u * sBC[t][s + 0]);
            h[s + 1] = fmaf(dA1, h[s + 1], u * sBC[t][s + 1]);
            h[s + 2] = fmaf(dA2, h[s + 2], u * sBC[t][s + 2]);
            h[s + 3] = fmaf(dA3, h[s + 3], u * sBC[t][s + 3]);
            y0 = fmaf(h[s + 0], sBC[t][16 + s + 0], y0);
            y1 = fmaf(h[s + 1], sBC[t][16 + s + 1], y1);
            y2 = fmaf(h[s + 2], sBC[t][16 + s + 2], y2);
            y3 = fmaf(h[s + 3], sBC[t][16 + s + 3], y3);
        }
        float y = (y0 + y1) + (y2 + y3) + xc * Dv;
        const float gate = zc * sigmoid_f(zc);
        yMb[(size_t)(m0 + t) * DINNER + d] = (__bf16)(y * gate);
        dtc = dtn; xc = xn; zc = zn;
    }
}

extern "C" void kernel_launch(void* const* d_in, const int* in_sizes, int n_in,
                              void* d_out, int out_size, void* d_ws, size_t ws_size,
                              hipStream_t stream) {
    const float* x         = (const float*)d_in[0];
    const float* in_proj_w = (const float*)d_in[1];
    const float* conv_w    = (const float*)d_in[2];
    const float* conv_b    = (const float*)d_in[3];
    const float* x_proj_w  = (const float*)d_in[4];
    const float* dt_proj_w = (const float*)d_in[5];
    const float* dt_proj_b = (const float*)d_in[6];
    const float* A_log     = (const float*)d_in[7];
    const float* D_param   = (const float*)d_in[8];
    const float* out_proj_w= (const float*)d_in[9];
    float* out = (float*)d_out;

    // ws layout (float units), no aliasing:
    // [0,4M)     xzb bf16 [2048][4096]
    // [4M,5M)    xb bf16     [5M,7M) wb_in bf16   [7M,8M) wb_out bf16
    // [8M,8.25M) wxp bf16 (96x2048)
    // [9M,11M)   xsb bf16    [11M,13M) dtb bf16
    // [13M,14M)  xdbl fp32 (zeroed in convert4, atomic-accumulated)
    // [14M,16M)  Pb fp32     [16M,18M) Bb fp32
    // [18M,20M)  yMb bf16
    float* ws = (float*)d_ws;
    const size_t M1 = (size_t)1024 * 1024;
    __bf16* xzb    = (__bf16*)ws;
    __bf16* xb     = (__bf16*)(ws + 4 * M1);
    __bf16* wb_in  = (__bf16*)(ws + 5 * M1);
    __bf16* wb_out = (__bf16*)(ws + 7 * M1);
    __bf16* wxp    = (__bf16*)(ws + 8 * M1);
    __bf16* xsb    = (__bf16*)(ws + 9 * M1);
    __bf16* dtb    = (__bf16*)(ws + 11 * M1);
    float*  xdbl   = ws + 13 * M1;
    float*  Pb     = ws + 14 * M1;
    float*  Bb     = ws + 16 * M1;
    __bf16* yMb    = (__bf16*)(ws + 18 * M1);

    dim3 blk(256);

    // 0. bf16 conversions + xdbl zero-init (one dispatch, 1097728 groups)
    convert4<<<dim3(4288), blk, 0, stream>>>(x, in_proj_w, out_proj_w, x_proj_w,
                                             xb, wb_in, wb_out, wxp, xdbl);

    // 1. in_proj (bf16 MFMA): xzb[m][4096] (bf16 out)
    mfma_gemm_bf16<128, __bf16><<<dim3((2 * DINNER) / 128, MTOK / 128), blk, 0, stream>>>(
        xb, DMODEL, wb_in, DMODEL, xzb, 2 * DINNER, DMODEL);

    // 2. causal conv + SiLU -> xsb bf16 (coalesced)
    conv_silu_kernel<<<dim3(B_SZ * T_LEN * DINNER / 256), blk, 0, stream>>>(xzb, conv_w, conv_b, xsb);

    // 3. x_proj (bf16 MFMA split-K, atomic): xdbl[m][96]
    mfma_xproj<<<dim3(3, MTOK / 128, XPK), blk, 0, stream>>>(xsb, wxp, xdbl);

    // 4. dt_proj: dtb[m][i] = bf16(softplus(...))
    gemm_dtproj<<<dim3(DINNER / 64, MTOK / 64), blk, 0, stream>>>(xdbl, dt_proj_w, dtb, dt_proj_b);

    // 5. chunked scan (fused gate+D epilogue in pass3) -> yMb bf16 [m][d]
    scan_pass1<<<dim3(NCH / 256, NC), blk, 0, stream>>>(dtb, xsb, xdbl, A_log, Pb, Bb);
    scan_pass2<<<dim3(NSTATES / 256), blk, 0, stream>>>(Pb, Bb);
    scan_pass3<<<dim3(NCH / 256, NC), blk, 0, stream>>>(dtb, xsb, xdbl, Bb, A_log, D_param, xzb, yMb);

    // 6. out_proj (bf16 MFMA): out[m][1024] (fp32 out)
    mfma_gemm_bf16<64, float><<<dim3(DMODEL / 64, MTOK / 128), blk, 0, stream>>>(
        yMb, DINNER, wb_out, DINNER, out, DMODEL, DINNER);
}